// Round 3
// baseline (328.328 us; speedup 1.0000x reference)
//
#include <hip/hip_runtime.h>

// Submanifold sparse conv 3x3x3, G=128, Cin=Cout=32.
// R9 == R8 resubmitted (container failed twice on infra; source audited for
// OOB/hang hazards and found clean, so rerun unchanged for attribution).
// R8: (a) conv at 512thr/__launch_bounds__(512,4) -> 128-VGPR budget, explicit
// 2x6 software pipeline of feature gathers (round-1's VGPR=32 forced a fully
// serial load->wait->MFMA chain: latency-bound at MfmaUtil 9%).
// (b) W^T LDS layout [k][half][quad][m]: a 16-lane read phase (quad fixed)
// touches 16 contiguous 16B slots = all 32 banks, killing the 8-way conflict
// (6.75M cycles, identical both prior rounds, was layout- not hoist-fixable).
// (c) scan kernel: coalesced int4 + shfl wave-scan (was stride-128B global
// reads on a single CU). (d) feature bf16 convert fused into scatter: linear
// read / scattered full-line 64B-row write (was a random-read extra pass).

#define GRID 128
#define CIN 32
#define COUT 32
#define NOFF 27
#define NBUCKET 32768   // (128/4)^3

typedef __attribute__((ext_vector_type(8))) short bf16x8;
typedef __attribute__((ext_vector_type(4))) float f32x4;

__device__ inline unsigned short f2bf(float x) {
    union { float f; unsigned u; } v; v.f = x;
    unsigned r = v.u + 0x7fff + ((v.u >> 16) & 1);   // RTNE
    return (unsigned short)(r >> 16);
}

__device__ inline unsigned spread3(unsigned v) {      // 5 bits -> every 3rd bit
    v &= 31u;
    v = (v | (v << 16)) & 0x030000FFu;
    v = (v | (v << 8))  & 0x0300F00Fu;
    v = (v | (v << 4))  & 0x030C30C3u;
    v = (v | (v << 2))  & 0x09249249u;
    return v;
}
__device__ inline int morton_bucket(int x, int y, int z) {
    return (int)(spread3(x >> 2) | (spread3(y >> 2) << 1) | (spread3(z >> 2) << 2));
}

// K1: table scatter (atomicMax = numpy max-index-wins), bucket histogram,
// weight transpose [27][ci][co] -> [k][half(co>=16)][quad(ci>>3)][m(co&15)][e(ci&7)].
__global__ void hist_kernel(const int* __restrict__ pos,
                            const float* __restrict__ wt,
                            int* __restrict__ table,
                            int* __restrict__ hist,
                            unsigned short* __restrict__ wtT, int N) {
    int i = blockIdx.x * 256 + threadIdx.x;
    if (i < N) {
        int x = pos[3 * i], y = pos[3 * i + 1], z = pos[3 * i + 2];
        int h = (x * GRID + y) * GRID + z;
        atomicMax(&table[h], i);
        atomicAdd(&hist[morton_bucket(x, y, z)], 1);
    }
    if (i < NOFF * CIN * COUT) {
        int k = i >> 10, r = i & 1023, ci = r >> 5, co = r & 31;
        int d = k * 1024 + (co >= 16 ? 512 : 0) + (ci >> 3) * 128 + (co & 15) * 8 + (ci & 7);
        wtT[d] = f2bf(wt[i]);
    }
}

// K2: exclusive scan of 32768 bucket counts. 1 block, 8 rounds of 4096,
// int4 coalesced loads + shfl wave scan (3 syncs/round).
__global__ __launch_bounds__(1024) void scan_kernel(int* __restrict__ hist) {
    __shared__ int wsum[16];
    int t = threadIdx.x, lane = t & 63, w = t >> 6;
    int carry = 0;
    for (int r = 0; r < 8; ++r) {
        int4 v = ((int4*)hist)[r * 1024 + t];
        int s0 = v.x, s1 = s0 + v.y, s2 = s1 + v.z, s3 = s2 + v.w;
        int s = s3;                                   // wave inclusive scan
        for (int off = 1; off < 64; off <<= 1) {
            int nv = __shfl_up(s, off, 64);
            if (lane >= off) s += nv;
        }
        if (lane == 63) wsum[w] = s;
        __syncthreads();
        if (w == 0) {
            int xx = (lane < 16) ? wsum[lane] : 0;
            for (int off = 1; off < 16; off <<= 1) {
                int nv = __shfl_up(xx, off, 64);
                if (lane >= off) xx += nv;
            }
            if (lane < 16) wsum[lane] = xx;
        }
        __syncthreads();
        int waveExcl = (w > 0 ? wsum[w - 1] : 0);
        int tot = wsum[15];
        int e = carry + waveExcl + (s - s3);          // thread-exclusive
        int4 o; o.x = e; o.y = e + s0; o.z = e + s1; o.w = e + s2;
        ((int4*)hist)[r * 1024 + t] = o;
        carry += tot;
        __syncthreads();                              // protect wsum for next round
    }
}

// K3: slot assignment + table winner-fixup + fused fp32->bf16 convert into
// sorted layout (linear 128B read per thread, scattered full-line 64B write).
__global__ void scatter_kernel(const int* __restrict__ pos,
                               int* __restrict__ hist,
                               int* __restrict__ table,
                               int* __restrict__ keyS,
                               int* __restrict__ origId,
                               const float* __restrict__ feats,
                               unsigned short* __restrict__ featsB, int N) {
    int i = blockIdx.x * 256 + threadIdx.x;
    if (i >= N) return;
    int x = pos[3 * i], y = pos[3 * i + 1], z = pos[3 * i + 2];
    int h = (x * GRID + y) * GRID + z;
    int slot = atomicAdd(&hist[morton_bucket(x, y, z)], 1);
    keyS[slot] = h;
    origId[slot] = i;
    if (table[h] == i) table[h] = -(slot + 2);        // winner encodes its slot
    const float4* s = (const float4*)(feats + (size_t)i * CIN);
    uint4* d = (uint4*)(featsB + (size_t)slot * CIN);
#pragma unroll
    for (int j = 0; j < 4; ++j) {
        float4 a = s[2 * j], b = s[2 * j + 1];
        uint4 o;
        o.x = (unsigned)f2bf(a.x) | ((unsigned)f2bf(a.y) << 16);
        o.y = (unsigned)f2bf(a.z) | ((unsigned)f2bf(a.w) << 16);
        o.z = (unsigned)f2bf(b.x) | ((unsigned)f2bf(b.y) << 16);
        o.w = (unsigned)f2bf(b.z) | ((unsigned)f2bf(b.w) << 16);
        d[j] = o;
    }
}

// K4: implicit-GEMM conv, one 16-pt sorted tile per wave, 8 waves/block.
// Weights in LDS (conflict-free layout); gathers 2x6 software-pipelined.
#define GATHER1(dst, kk) { \
    int r_ = rows[kk]; \
    const unsigned short* p_ = featsB + (r_ < 0 ? 0 : r_) + quad * 8; \
    bf16x8 t_ = *(const bf16x8*)p_; \
    if (r_ < 0) t_ = z8; \
    dst = t_; }

#define STEP1(areg, kk) { \
    bf16x8 b0_ = *(const bf16x8*)(wb + (kk) * 1024); \
    bf16x8 b1_ = *(const bf16x8*)(wb + (kk) * 1024 + 512); \
    acc0 = __builtin_amdgcn_mfma_f32_16x16x32_bf16(areg, b0_, acc0, 0, 0, 0); \
    acc1 = __builtin_amdgcn_mfma_f32_16x16x32_bf16(areg, b1_, acc1, 0, 0, 0); }

__global__ __launch_bounds__(512, 4)
void conv_kernel(const unsigned short* __restrict__ featsB,
                 const int* __restrict__ keyS,
                 const unsigned short* __restrict__ wtT,
                 const int* __restrict__ table,
                 const int* __restrict__ origId,
                 float* __restrict__ out, int N) {
    __shared__ __align__(16) unsigned short ldsw[NOFF * 1024]; // 55296 B

    // XCD-bijective swizzle (m204): contiguous Morton chunk per XCD.
    int nwg = (int)gridDim.x;
    int orig = (int)blockIdx.x;
    int q8 = nwg >> 3, r8 = nwg & 7;
    int xcd = orig & 7, lin = orig >> 3;
    int bid = (xcd < r8 ? xcd * (q8 + 1) : r8 * (q8 + 1) + (xcd - r8) * q8) + lin;

    int tid = threadIdx.x;
    int wave = tid >> 6, lane = tid & 63;
    int m = lane & 15, quad = lane >> 4;
    int tile = bid * 8 + wave;
    int base = tile * 16;
    int g = base + m;
    bool gv = g < N;

    int key = gv ? keyS[g] : 0;               // key == (x*128+y)*128+z
    int x = key >> 14, y = (key >> 7) & 127, z = key & 127;
    bool v0[3] = {gv && x > 0, gv, gv && x < GRID - 1};
    bool v1[3] = {gv && y > 0, gv, gv && y < GRID - 1};
    bool v2[3] = {gv && z > 0, gv, gv && z < GRID - 1};

    // Phase A: 27 independent table lookups in flight over the LDS staging.
    int rows[NOFF];
#pragma unroll
    for (int k = 0; k < NOFF; ++k) {
        const int dx = k / 9, dy = (k / 3) % 3, dz = k % 3;
        bool ok = v0[dx] && v1[dy] && v2[dz];
        int hk = key + (dx - 1) * GRID * GRID + (dy - 1) * GRID + (dz - 1);
        hk = ok ? hk : 0;
        int id = table[hk];                   // -1 empty, -(slot+2) occupied
        rows[k] = (ok && id < -1) ? (-id - 2) * CIN : -1;
    }

    // Stage W^T (already in [k][half][quad][m] order) into LDS.
    {
        const uint4* src = (const uint4*)wtT;   // 3456 x 16B
        uint4* dst = (uint4*)ldsw;
        for (int e = tid; e < NOFF * 1024 * 2 / 16; e += 512) dst[e] = src[e];
    }
    __syncthreads();

    f32x4 acc0 = {0.f, 0.f, 0.f, 0.f};
    f32x4 acc1 = {0.f, 0.f, 0.f, 0.f};
    const bf16x8 z8 = {0, 0, 0, 0, 0, 0, 0, 0};
    // conflict-free: 16-lane phase (quad fixed) reads 16 contiguous 16B slots
    const unsigned short* wb = ldsw + quad * 128 + m * 8;

    bf16x8 A0, A1, A2, A3, A4, A5, B0, B1, B2, B3, B4, B5;
    // chunk 0 -> A
    GATHER1(A0, 0)  GATHER1(A1, 1)  GATHER1(A2, 2)
    GATHER1(A3, 3)  GATHER1(A4, 4)  GATHER1(A5, 5)
    // chunk 1 -> B, compute chunk 0
    GATHER1(B0, 6)  GATHER1(B1, 7)  GATHER1(B2, 8)
    GATHER1(B3, 9)  GATHER1(B4, 10) GATHER1(B5, 11)
    STEP1(A0, 0)  STEP1(A1, 1)  STEP1(A2, 2)
    STEP1(A3, 3)  STEP1(A4, 4)  STEP1(A5, 5)
    // chunk 2 -> A, compute chunk 1
    GATHER1(A0, 12) GATHER1(A1, 13) GATHER1(A2, 14)
    GATHER1(A3, 15) GATHER1(A4, 16) GATHER1(A5, 17)
    STEP1(B0, 6)  STEP1(B1, 7)  STEP1(B2, 8)
    STEP1(B3, 9)  STEP1(B4, 10) STEP1(B5, 11)
    // chunk 3 -> B, compute chunk 2
    GATHER1(B0, 18) GATHER1(B1, 19) GATHER1(B2, 20)
    GATHER1(B3, 21) GATHER1(B4, 22) GATHER1(B5, 23)
    STEP1(A0, 12) STEP1(A1, 13) STEP1(A2, 14)
    STEP1(A3, 15) STEP1(A4, 16) STEP1(A5, 17)
    // chunk 4 (3 wide) -> A, compute chunk 3
    GATHER1(A0, 24) GATHER1(A1, 25) GATHER1(A2, 26)
    STEP1(B0, 18) STEP1(B1, 19) STEP1(B2, 20)
    STEP1(B3, 21) STEP1(B4, 22) STEP1(B5, 23)
    // compute chunk 4
    STEP1(A0, 24) STEP1(A1, 25) STEP1(A2, 26)

    // D layout: col = lane&15 = co, row = quad*4 + i = slot within tile.
#pragma unroll
    for (int i = 0; i < 4; ++i) {
        int p = base + quad * 4 + i;
        if (p < N) {
            int o = origId[p];
            out[(size_t)o * COUT + m]      = acc0[i];
            out[(size_t)o * COUT + m + 16] = acc1[i];
        }
    }
}

extern "C" void kernel_launch(void* const* d_in, const int* in_sizes, int n_in,
                              void* d_out, int out_size, void* d_ws, size_t ws_size,
                              hipStream_t stream) {
    const float* feats = (const float*)d_in[0];   // [N, 32]
    const int*   pos   = (const int*)d_in[1];     // [N, 3]
    const float* wt    = (const float*)d_in[2];   // [27, 32, 32]
    float* out = (float*)d_out;                   // [N, 32]
    int N = in_sizes[0] / CIN;

    char* ws = (char*)d_ws;
    size_t off = 0;
    int* table = (int*)(ws + off);            off += (size_t)GRID * GRID * GRID * 4; // 8 MB
    unsigned short* wtT = (unsigned short*)(ws + off); off += 65536;                 // 64 KB
    int* hist = (int*)(ws + off);             off += NBUCKET * 4;                    // 128 KB
    int* keyS = (int*)(ws + off);             off += 2097152;                        // 2 MB
    int* origId = (int*)(ws + off);           off += 2097152;                        // 2 MB
    unsigned short* featsB = (unsigned short*)(ws + off);                            // 32 MB

    hipMemsetAsync(table, 0xFF, (size_t)GRID * GRID * GRID * 4, stream);
    hipMemsetAsync(hist, 0, NBUCKET * 4, stream);

    int blocksN = (N + 255) / 256;
    hist_kernel<<<blocksN, 256, 0, stream>>>(pos, wt, table, hist, wtT, N);
    scan_kernel<<<1, 1024, 0, stream>>>(hist);
    scatter_kernel<<<blocksN, 256, 0, stream>>>(pos, hist, table, keyS, origId,
                                                feats, featsB, N);

    int numTiles = (N + 15) / 16;
    int nwg = (numTiles + 7) / 8;     // 8 waves (512 threads) per block
    conv_kernel<<<nwg, 512, 0, stream>>>(featsB, keyS, wtT, table, origId, out, N);
}

// Round 4
// 325.364 us; speedup vs baseline: 1.0091x; 1.0091x over previous
//
#include <hip/hip_runtime.h>

// Submanifold sparse conv 3x3x3, G=128, Cin=Cout=32.
// R10: R9 + sched_barrier(0)-pinned gather pipeline. R9 evidence: VGPR=52
// (compiler sank all 12 pipeline buffers to just-in-time loads -> serial
// vmcnt(0) chain, MfmaUtil 8.5%, dur unchanged 127us despite 0 bank
// conflicts). Fix: __builtin_amdgcn_sched_barrier(0) between every
// GATHER/STEP cluster pins the 2x6 pipeline; hardware waits become counted
// vmcnt(6); first chunk issued BEFORE LDS staging so its latency hides there.
// Success criterion: VGPR ~96-120, conv ~45-65us. If VGPR stays ~52 the pin
// failed.

#define GRID 128
#define CIN 32
#define COUT 32
#define NOFF 27
#define NBUCKET 32768   // (128/4)^3

typedef __attribute__((ext_vector_type(8))) short bf16x8;
typedef __attribute__((ext_vector_type(4))) float f32x4;

__device__ inline unsigned short f2bf(float x) {
    union { float f; unsigned u; } v; v.f = x;
    unsigned r = v.u + 0x7fff + ((v.u >> 16) & 1);   // RTNE
    return (unsigned short)(r >> 16);
}

__device__ inline unsigned spread3(unsigned v) {      // 5 bits -> every 3rd bit
    v &= 31u;
    v = (v | (v << 16)) & 0x030000FFu;
    v = (v | (v << 8))  & 0x0300F00Fu;
    v = (v | (v << 4))  & 0x030C30C3u;
    v = (v | (v << 2))  & 0x09249249u;
    return v;
}
__device__ inline int morton_bucket(int x, int y, int z) {
    return (int)(spread3(x >> 2) | (spread3(y >> 2) << 1) | (spread3(z >> 2) << 2));
}

// K1: table scatter (atomicMax = numpy max-index-wins), bucket histogram,
// weight transpose [27][ci][co] -> [k][half(co>=16)][quad(ci>>3)][m(co&15)][e(ci&7)].
__global__ void hist_kernel(const int* __restrict__ pos,
                            const float* __restrict__ wt,
                            int* __restrict__ table,
                            int* __restrict__ hist,
                            unsigned short* __restrict__ wtT, int N) {
    int i = blockIdx.x * 256 + threadIdx.x;
    if (i < N) {
        int x = pos[3 * i], y = pos[3 * i + 1], z = pos[3 * i + 2];
        int h = (x * GRID + y) * GRID + z;
        atomicMax(&table[h], i);
        atomicAdd(&hist[morton_bucket(x, y, z)], 1);
    }
    if (i < NOFF * CIN * COUT) {
        int k = i >> 10, r = i & 1023, ci = r >> 5, co = r & 31;
        int d = k * 1024 + (co >= 16 ? 512 : 0) + (ci >> 3) * 128 + (co & 15) * 8 + (ci & 7);
        wtT[d] = f2bf(wt[i]);
    }
}

// K2: exclusive scan of 32768 bucket counts. 1 block, 8 rounds of 4096,
// int4 coalesced loads + shfl wave scan.
__global__ __launch_bounds__(1024) void scan_kernel(int* __restrict__ hist) {
    __shared__ int wsum[16];
    int t = threadIdx.x, lane = t & 63, w = t >> 6;
    int carry = 0;
    for (int r = 0; r < 8; ++r) {
        int4 v = ((int4*)hist)[r * 1024 + t];
        int s0 = v.x, s1 = s0 + v.y, s2 = s1 + v.z, s3 = s2 + v.w;
        int s = s3;                                   // wave inclusive scan
        for (int off = 1; off < 64; off <<= 1) {
            int nv = __shfl_up(s, off, 64);
            if (lane >= off) s += nv;
        }
        if (lane == 63) wsum[w] = s;
        __syncthreads();
        if (w == 0) {
            int xx = (lane < 16) ? wsum[lane] : 0;
            for (int off = 1; off < 16; off <<= 1) {
                int nv = __shfl_up(xx, off, 64);
                if (lane >= off) xx += nv;
            }
            if (lane < 16) wsum[lane] = xx;
        }
        __syncthreads();
        int waveExcl = (w > 0 ? wsum[w - 1] : 0);
        int tot = wsum[15];
        int e = carry + waveExcl + (s - s3);          // thread-exclusive
        int4 o; o.x = e; o.y = e + s0; o.z = e + s1; o.w = e + s2;
        ((int4*)hist)[r * 1024 + t] = o;
        carry += tot;
        __syncthreads();                              // protect wsum for next round
    }
}

// K3: slot assignment + table winner-fixup + fused fp32->bf16 convert into
// sorted layout (linear 128B read per thread, scattered full-line 64B write).
__global__ void scatter_kernel(const int* __restrict__ pos,
                               int* __restrict__ hist,
                               int* __restrict__ table,
                               int* __restrict__ keyS,
                               int* __restrict__ origId,
                               const float* __restrict__ feats,
                               unsigned short* __restrict__ featsB, int N) {
    int i = blockIdx.x * 256 + threadIdx.x;
    if (i >= N) return;
    int x = pos[3 * i], y = pos[3 * i + 1], z = pos[3 * i + 2];
    int h = (x * GRID + y) * GRID + z;
    int slot = atomicAdd(&hist[morton_bucket(x, y, z)], 1);
    keyS[slot] = h;
    origId[slot] = i;
    if (table[h] == i) table[h] = -(slot + 2);        // winner encodes its slot
    const float4* s = (const float4*)(feats + (size_t)i * CIN);
    uint4* d = (uint4*)(featsB + (size_t)slot * CIN);
#pragma unroll
    for (int j = 0; j < 4; ++j) {
        float4 a = s[2 * j], b = s[2 * j + 1];
        uint4 o;
        o.x = (unsigned)f2bf(a.x) | ((unsigned)f2bf(a.y) << 16);
        o.y = (unsigned)f2bf(a.z) | ((unsigned)f2bf(a.w) << 16);
        o.z = (unsigned)f2bf(b.x) | ((unsigned)f2bf(b.y) << 16);
        o.w = (unsigned)f2bf(b.z) | ((unsigned)f2bf(b.w) << 16);
        d[j] = o;
    }
}

// K4: implicit-GEMM conv, one 16-pt sorted tile per wave, 8 waves/block.
// Weights in LDS (conflict-free layout); gathers 2x6 pipeline pinned with
// sched_barrier(0) so the allocator keeps 6 loads in flight (vmcnt(6) waits).
#define SBAR() __builtin_amdgcn_sched_barrier(0)

#define GATHER1(dst, kk) { \
    int r_ = rows[kk]; \
    const unsigned short* p_ = featsB + (r_ < 0 ? 0 : r_) + quad * 8; \
    bf16x8 t_ = *(const bf16x8*)p_; \
    if (r_ < 0) t_ = z8; \
    dst = t_; }

#define STEP1(areg, kk) { \
    bf16x8 b0_ = *(const bf16x8*)(wb + (kk) * 1024); \
    bf16x8 b1_ = *(const bf16x8*)(wb + (kk) * 1024 + 512); \
    acc0 = __builtin_amdgcn_mfma_f32_16x16x32_bf16(areg, b0_, acc0, 0, 0, 0); \
    acc1 = __builtin_amdgcn_mfma_f32_16x16x32_bf16(areg, b1_, acc1, 0, 0, 0); }

__global__ __launch_bounds__(512, 4)
void conv_kernel(const unsigned short* __restrict__ featsB,
                 const int* __restrict__ keyS,
                 const unsigned short* __restrict__ wtT,
                 const int* __restrict__ table,
                 const int* __restrict__ origId,
                 float* __restrict__ out, int N) {
    __shared__ __align__(16) unsigned short ldsw[NOFF * 1024]; // 55296 B

    // XCD-bijective swizzle (m204): contiguous Morton chunk per XCD.
    int nwg = (int)gridDim.x;
    int orig = (int)blockIdx.x;
    int q8 = nwg >> 3, r8 = nwg & 7;
    int xcd = orig & 7, lin = orig >> 3;
    int bid = (xcd < r8 ? xcd * (q8 + 1) : r8 * (q8 + 1) + (xcd - r8) * q8) + lin;

    int tid = threadIdx.x;
    int wave = tid >> 6, lane = tid & 63;
    int m = lane & 15, quad = lane >> 4;
    int tile = bid * 8 + wave;
    int base = tile * 16;
    int g = base + m;
    bool gv = g < N;

    int key = gv ? keyS[g] : 0;               // key == (x*128+y)*128+z
    int x = key >> 14, y = (key >> 7) & 127, z = key & 127;
    bool v0[3] = {gv && x > 0, gv, gv && x < GRID - 1};
    bool v1[3] = {gv && y > 0, gv, gv && y < GRID - 1};
    bool v2[3] = {gv && z > 0, gv, gv && z < GRID - 1};

    // Phase A: 27 independent table lookups (MLP).
    int rows[NOFF];
#pragma unroll
    for (int k = 0; k < NOFF; ++k) {
        const int dx = k / 9, dy = (k / 3) % 3, dz = k % 3;
        bool ok = v0[dx] && v1[dy] && v2[dz];
        int hk = key + (dx - 1) * GRID * GRID + (dy - 1) * GRID + (dz - 1);
        hk = ok ? hk : 0;
        int id = table[hk];                   // -1 empty, -(slot+2) occupied
        rows[k] = (ok && id < -1) ? (-id - 2) * CIN : -1;
    }

    f32x4 acc0 = {0.f, 0.f, 0.f, 0.f};
    f32x4 acc1 = {0.f, 0.f, 0.f, 0.f};
    const bf16x8 z8 = {0, 0, 0, 0, 0, 0, 0, 0};
    bf16x8 A0, A1, A2, A3, A4, A5, B0, B1, B2, B3, B4, B5;

    // chunk 0 issued BEFORE staging: its latency hides under the LDS stage.
    GATHER1(A0, 0)  GATHER1(A1, 1)  GATHER1(A2, 2)
    GATHER1(A3, 3)  GATHER1(A4, 4)  GATHER1(A5, 5)
    SBAR();

    // Stage W^T (already in [k][half][quad][m] order) into LDS.
    {
        const uint4* src = (const uint4*)wtT;   // 3456 x 16B
        uint4* dst = (uint4*)ldsw;
        for (int e = tid; e < NOFF * 1024 * 2 / 16; e += 512) dst[e] = src[e];
    }
    __syncthreads();

    // conflict-free: 16-lane phase (quad fixed) reads 16 contiguous 16B slots
    const unsigned short* wb = ldsw + quad * 128 + m * 8;

    GATHER1(B0, 6)  GATHER1(B1, 7)  GATHER1(B2, 8)
    GATHER1(B3, 9)  GATHER1(B4, 10) GATHER1(B5, 11)
    SBAR();
    STEP1(A0, 0)  STEP1(A1, 1)  STEP1(A2, 2)
    STEP1(A3, 3)  STEP1(A4, 4)  STEP1(A5, 5)
    SBAR();
    GATHER1(A0, 12) GATHER1(A1, 13) GATHER1(A2, 14)
    GATHER1(A3, 15) GATHER1(A4, 16) GATHER1(A5, 17)
    SBAR();
    STEP1(B0, 6)  STEP1(B1, 7)  STEP1(B2, 8)
    STEP1(B3, 9)  STEP1(B4, 10) STEP1(B5, 11)
    SBAR();
    GATHER1(B0, 18) GATHER1(B1, 19) GATHER1(B2, 20)
    GATHER1(B3, 21) GATHER1(B4, 22) GATHER1(B5, 23)
    SBAR();
    STEP1(A0, 12) STEP1(A1, 13) STEP1(A2, 14)
    STEP1(A3, 15) STEP1(A4, 16) STEP1(A5, 17)
    SBAR();
    GATHER1(A0, 24) GATHER1(A1, 25) GATHER1(A2, 26)
    SBAR();
    STEP1(B0, 18) STEP1(B1, 19) STEP1(B2, 20)
    STEP1(B3, 21) STEP1(B4, 22) STEP1(B5, 23)
    SBAR();
    STEP1(A0, 24) STEP1(A1, 25) STEP1(A2, 26)

    // D layout: col = lane&15 = co, row = quad*4 + i = slot within tile.
#pragma unroll
    for (int i = 0; i < 4; ++i) {
        int p = base + quad * 4 + i;
        if (p < N) {
            int o = origId[p];
            out[(size_t)o * COUT + m]      = acc0[i];
            out[(size_t)o * COUT + m + 16] = acc1[i];
        }
    }
}

extern "C" void kernel_launch(void* const* d_in, const int* in_sizes, int n_in,
                              void* d_out, int out_size, void* d_ws, size_t ws_size,
                              hipStream_t stream) {
    const float* feats = (const float*)d_in[0];   // [N, 32]
    const int*   pos   = (const int*)d_in[1];     // [N, 3]
    const float* wt    = (const float*)d_in[2];   // [27, 32, 32]
    float* out = (float*)d_out;                   // [N, 32]
    int N = in_sizes[0] / CIN;

    char* ws = (char*)d_ws;
    size_t off = 0;
    int* table = (int*)(ws + off);            off += (size_t)GRID * GRID * GRID * 4; // 8 MB
    unsigned short* wtT = (unsigned short*)(ws + off); off += 65536;                 // 64 KB
    int* hist = (int*)(ws + off);             off += NBUCKET * 4;                    // 128 KB
    int* keyS = (int*)(ws + off);             off += 2097152;                        // 2 MB
    int* origId = (int*)(ws + off);           off += 2097152;                        // 2 MB
    unsigned short* featsB = (unsigned short*)(ws + off);                            // 32 MB

    hipMemsetAsync(table, 0xFF, (size_t)GRID * GRID * GRID * 4, stream);
    hipMemsetAsync(hist, 0, NBUCKET * 4, stream);

    int blocksN = (N + 255) / 256;
    hist_kernel<<<blocksN, 256, 0, stream>>>(pos, wt, table, hist, wtT, N);
    scan_kernel<<<1, 1024, 0, stream>>>(hist);
    scatter_kernel<<<blocksN, 256, 0, stream>>>(pos, hist, table, keyS, origId,
                                                feats, featsB, N);

    int numTiles = (N + 15) / 16;
    int nwg = (numTiles + 7) / 8;     // 8 waves (512 threads) per block
    conv_kernel<<<nwg, 512, 0, stream>>>(featsB, keyS, wtT, table, origId, out, N);
}

// Round 5
// 325.157 us; speedup vs baseline: 1.0098x; 1.0006x over previous
//
#include <hip/hip_runtime.h>

// Submanifold sparse conv 3x3x3, G=128, Cin=Cout=32.
// R11: manual asm gather pipeline. R10 evidence: sched_barrier(0) alone did
// NOT pin the pipeline (VGPR stayed 52 = compiler re-sank loads just-in-time;
// serial vmcnt(0) chain; MfmaUtil 8.7%, 124us). Fix: gathers issued as
// asm volatile global_load_dwordx4 (un-sinkable), rolling 13-deep window,
// hand-counted s_waitcnt vmcnt(12..0) + sched_barrier(0) per step (rule #18).
// Zero-row trick: featsB row 0 = zeros, slots shifted +1, so invalid
// neighbors load row 0 -> no per-gather select, asm output feeds MFMA.
// Loop region has no compiler vmem ops (weights via ds_read/lgkmcnt), so the
// vmcnt bookkeeping is exact; __launch_bounds__(512,3) avoids spill risk.
// Success criterion: VGPR ~100-130, conv 40-65us. VGPR ~52 again = pin failed.

#define GRID 128
#define CIN 32
#define COUT 32
#define NOFF 27
#define NBUCKET 32768   // (128/4)^3

typedef __attribute__((ext_vector_type(8))) short bf16x8;
typedef __attribute__((ext_vector_type(4))) float f32x4;

__device__ inline unsigned short f2bf(float x) {
    union { float f; unsigned u; } v; v.f = x;
    unsigned r = v.u + 0x7fff + ((v.u >> 16) & 1);   // RTNE
    return (unsigned short)(r >> 16);
}

__device__ inline unsigned spread3(unsigned v) {      // 5 bits -> every 3rd bit
    v &= 31u;
    v = (v | (v << 16)) & 0x030000FFu;
    v = (v | (v << 8))  & 0x0300F00Fu;
    v = (v | (v << 4))  & 0x030C30C3u;
    v = (v | (v << 2))  & 0x09249249u;
    return v;
}
__device__ inline int morton_bucket(int x, int y, int z) {
    return (int)(spread3(x >> 2) | (spread3(y >> 2) << 1) | (spread3(z >> 2) << 2));
}

// K1: table scatter (atomicMax = numpy max-index-wins), bucket histogram,
// weight transpose [27][ci][co] -> [k][half(co>=16)][quad(ci>>3)][m(co&15)][e(ci&7)].
__global__ void hist_kernel(const int* __restrict__ pos,
                            const float* __restrict__ wt,
                            int* __restrict__ table,
                            int* __restrict__ hist,
                            unsigned short* __restrict__ wtT, int N) {
    int i = blockIdx.x * 256 + threadIdx.x;
    if (i < N) {
        int x = pos[3 * i], y = pos[3 * i + 1], z = pos[3 * i + 2];
        int h = (x * GRID + y) * GRID + z;
        atomicMax(&table[h], i);
        atomicAdd(&hist[morton_bucket(x, y, z)], 1);
    }
    if (i < NOFF * CIN * COUT) {
        int k = i >> 10, r = i & 1023, ci = r >> 5, co = r & 31;
        int d = k * 1024 + (co >= 16 ? 512 : 0) + (ci >> 3) * 128 + (co & 15) * 8 + (ci & 7);
        wtT[d] = f2bf(wt[i]);
    }
}

// K2: exclusive scan of 32768 bucket counts. 1 block, 8 rounds of 4096,
// int4 coalesced loads + shfl wave scan.
__global__ __launch_bounds__(1024) void scan_kernel(int* __restrict__ hist) {
    __shared__ int wsum[16];
    int t = threadIdx.x, lane = t & 63, w = t >> 6;
    int carry = 0;
    for (int r = 0; r < 8; ++r) {
        int4 v = ((int4*)hist)[r * 1024 + t];
        int s0 = v.x, s1 = s0 + v.y, s2 = s1 + v.z, s3 = s2 + v.w;
        int s = s3;                                   // wave inclusive scan
        for (int off = 1; off < 64; off <<= 1) {
            int nv = __shfl_up(s, off, 64);
            if (lane >= off) s += nv;
        }
        if (lane == 63) wsum[w] = s;
        __syncthreads();
        if (w == 0) {
            int xx = (lane < 16) ? wsum[lane] : 0;
            for (int off = 1; off < 16; off <<= 1) {
                int nv = __shfl_up(xx, off, 64);
                if (lane >= off) xx += nv;
            }
            if (lane < 16) wsum[lane] = xx;
        }
        __syncthreads();
        int waveExcl = (w > 0 ? wsum[w - 1] : 0);
        int tot = wsum[15];
        int e = carry + waveExcl + (s - s3);          // thread-exclusive
        int4 o; o.x = e; o.y = e + s0; o.z = e + s1; o.w = e + s2;
        ((int4*)hist)[r * 1024 + t] = o;
        carry += tot;
        __syncthreads();                              // protect wsum for next round
    }
}

// K3: slot assignment + table winner-fixup + fused fp32->bf16 convert into
// sorted layout at row slot+1 (row 0 is the shared zero row).
__global__ void scatter_kernel(const int* __restrict__ pos,
                               int* __restrict__ hist,
                               int* __restrict__ table,
                               int* __restrict__ keyS,
                               int* __restrict__ origId,
                               const float* __restrict__ feats,
                               unsigned short* __restrict__ featsB, int N) {
    int i = blockIdx.x * 256 + threadIdx.x;
    if (i >= N) return;
    int x = pos[3 * i], y = pos[3 * i + 1], z = pos[3 * i + 2];
    int h = (x * GRID + y) * GRID + z;
    int slot = atomicAdd(&hist[morton_bucket(x, y, z)], 1);
    keyS[slot] = h;
    origId[slot] = i;
    if (table[h] == i) table[h] = -(slot + 2);        // winner encodes its slot
    const float4* s = (const float4*)(feats + (size_t)i * CIN);
    uint4* d = (uint4*)(featsB + ((size_t)slot + 1) * CIN);   // +1: zero row 0
#pragma unroll
    for (int j = 0; j < 4; ++j) {
        float4 a = s[2 * j], b = s[2 * j + 1];
        uint4 o;
        o.x = (unsigned)f2bf(a.x) | ((unsigned)f2bf(a.y) << 16);
        o.y = (unsigned)f2bf(a.z) | ((unsigned)f2bf(a.w) << 16);
        o.z = (unsigned)f2bf(b.x) | ((unsigned)f2bf(b.y) << 16);
        o.w = (unsigned)f2bf(b.z) | ((unsigned)f2bf(b.w) << 16);
        d[j] = o;
    }
}

// K4: implicit-GEMM conv, one 16-pt sorted tile per wave, 8 waves/block.
// Gathers: asm global_load_dwordx4, 13-deep rolling window, counted vmcnt.
#define SBAR() __builtin_amdgcn_sched_barrier(0)
#define WAITV(n) asm volatile("s_waitcnt vmcnt(" #n ")" ::: "memory")
#define GLOAD(dst, kk) { \
    const unsigned short* p_ = featsB + rows[kk] + qoff; \
    asm volatile("global_load_dwordx4 %0, %1, off" : "=v"(dst) : "v"(p_)); }

#define STEP1(areg, kk) { \
    bf16x8 b0_ = *(const bf16x8*)(wb + (kk) * 1024); \
    bf16x8 b1_ = *(const bf16x8*)(wb + (kk) * 1024 + 512); \
    acc0 = __builtin_amdgcn_mfma_f32_16x16x32_bf16(areg, b0_, acc0, 0, 0, 0); \
    acc1 = __builtin_amdgcn_mfma_f32_16x16x32_bf16(areg, b1_, acc1, 0, 0, 0); }

__global__ __launch_bounds__(512, 3)
void conv_kernel(const unsigned short* __restrict__ featsB,
                 const int* __restrict__ keyS,
                 const unsigned short* __restrict__ wtT,
                 const int* __restrict__ table,
                 const int* __restrict__ origId,
                 float* __restrict__ out, int N) {
    __shared__ __align__(16) unsigned short ldsw[NOFF * 1024]; // 55296 B

    // XCD-bijective swizzle (m204): contiguous Morton chunk per XCD.
    int nwg = (int)gridDim.x;
    int orig = (int)blockIdx.x;
    int q8 = nwg >> 3, r8 = nwg & 7;
    int xcd = orig & 7, lin = orig >> 3;
    int bid = (xcd < r8 ? xcd * (q8 + 1) : r8 * (q8 + 1) + (xcd - r8) * q8) + lin;

    int tid = threadIdx.x;
    int wave = tid >> 6, lane = tid & 63;
    int m = lane & 15, quad = lane >> 4;
    int qoff = quad * 8;
    int tile = bid * 8 + wave;
    int base = tile * 16;
    int g = base + m;
    bool gv = g < N;

    int key = gv ? keyS[g] : 0;               // key == (x*128+y)*128+z
    int x = key >> 14, y = (key >> 7) & 127, z = key & 127;
    bool v0[3] = {gv && x > 0, gv, gv && x < GRID - 1};
    bool v1[3] = {gv && y > 0, gv, gv && y < GRID - 1};
    bool v2[3] = {gv && z > 0, gv, gv && z < GRID - 1};

    // Phase A: 27 independent table lookups (MLP).
    int rows[NOFF];
#pragma unroll
    for (int k = 0; k < NOFF; ++k) {
        const int dx = k / 9, dy = (k / 3) % 3, dz = k % 3;
        bool ok = v0[dx] && v1[dy] && v2[dz];
        int hk = key + (dx - 1) * GRID * GRID + (dy - 1) * GRID + (dz - 1);
        hk = ok ? hk : 0;
        int id = table[hk];                   // -1 empty, -(slot+2) occupied
        rows[k] = (ok && id < -1) ? (-id - 1) * CIN : 0;   // (slot+1)*CIN; 0 = zero row
    }

    f32x4 acc0 = {0.f, 0.f, 0.f, 0.f};
    f32x4 acc1 = {0.f, 0.f, 0.f, 0.f};
    bf16x8 b0, b1, b2, b3, b4, b5, b6, b7, b8, b9, b10, b11, b12;

    // Prologue: gathers 0..12 issued; latency hides under the LDS stage.
    GLOAD(b0, 0)   GLOAD(b1, 1)   GLOAD(b2, 2)   GLOAD(b3, 3)
    GLOAD(b4, 4)   GLOAD(b5, 5)   GLOAD(b6, 6)   GLOAD(b7, 7)
    GLOAD(b8, 8)   GLOAD(b9, 9)   GLOAD(b10, 10) GLOAD(b11, 11)
    GLOAD(b12, 12)

    // Stage W^T (already in [k][half][quad][m] order) into LDS.
    {
        const uint4* src = (const uint4*)wtT;   // 3456 x 16B
        uint4* dst = (uint4*)ldsw;
        for (int e = tid; e < NOFF * 1024 * 2 / 16; e += 512) dst[e] = src[e];
    }
    __syncthreads();

    // conflict-free: 16-lane phase (quad fixed) reads 16 contiguous 16B slots
    const unsigned short* wb = ldsw + quad * 128 + m * 8;

    // Steady state: consume b[k%13], reload gather k+13 into the same slot.
    WAITV(12); SBAR(); STEP1(b0, 0)   GLOAD(b0, 13)
    WAITV(12); SBAR(); STEP1(b1, 1)   GLOAD(b1, 14)
    WAITV(12); SBAR(); STEP1(b2, 2)   GLOAD(b2, 15)
    WAITV(12); SBAR(); STEP1(b3, 3)   GLOAD(b3, 16)
    WAITV(12); SBAR(); STEP1(b4, 4)   GLOAD(b4, 17)
    WAITV(12); SBAR(); STEP1(b5, 5)   GLOAD(b5, 18)
    WAITV(12); SBAR(); STEP1(b6, 6)   GLOAD(b6, 19)
    WAITV(12); SBAR(); STEP1(b7, 7)   GLOAD(b7, 20)
    WAITV(12); SBAR(); STEP1(b8, 8)   GLOAD(b8, 21)
    WAITV(12); SBAR(); STEP1(b9, 9)   GLOAD(b9, 22)
    WAITV(12); SBAR(); STEP1(b10, 10) GLOAD(b10, 23)
    WAITV(12); SBAR(); STEP1(b11, 11) GLOAD(b11, 24)
    WAITV(12); SBAR(); STEP1(b12, 12) GLOAD(b12, 25)
    WAITV(12); SBAR(); STEP1(b0, 13)  GLOAD(b0, 26)
    WAITV(12); SBAR(); STEP1(b1, 14)
    WAITV(11); SBAR(); STEP1(b2, 15)
    WAITV(10); SBAR(); STEP1(b3, 16)
    WAITV(9);  SBAR(); STEP1(b4, 17)
    WAITV(8);  SBAR(); STEP1(b5, 18)
    WAITV(7);  SBAR(); STEP1(b6, 19)
    WAITV(6);  SBAR(); STEP1(b7, 20)
    WAITV(5);  SBAR(); STEP1(b8, 21)
    WAITV(4);  SBAR(); STEP1(b9, 22)
    WAITV(3);  SBAR(); STEP1(b10, 23)
    WAITV(2);  SBAR(); STEP1(b11, 24)
    WAITV(1);  SBAR(); STEP1(b12, 25)
    WAITV(0);  SBAR(); STEP1(b0, 26)

    // D layout: col = lane&15 = co, row = quad*4 + i = slot within tile.
#pragma unroll
    for (int i = 0; i < 4; ++i) {
        int p = base + quad * 4 + i;
        if (p < N) {
            int o = origId[p];
            out[(size_t)o * COUT + m]      = acc0[i];
            out[(size_t)o * COUT + m + 16] = acc1[i];
        }
    }
}

extern "C" void kernel_launch(void* const* d_in, const int* in_sizes, int n_in,
                              void* d_out, int out_size, void* d_ws, size_t ws_size,
                              hipStream_t stream) {
    const float* feats = (const float*)d_in[0];   // [N, 32]
    const int*   pos   = (const int*)d_in[1];     // [N, 3]
    const float* wt    = (const float*)d_in[2];   // [27, 32, 32]
    float* out = (float*)d_out;                   // [N, 32]
    int N = in_sizes[0] / CIN;

    char* ws = (char*)d_ws;
    size_t off = 0;
    int* table = (int*)(ws + off);            off += (size_t)GRID * GRID * GRID * 4; // 8 MB
    unsigned short* wtT = (unsigned short*)(ws + off); off += 65536;                 // 64 KB
    int* hist = (int*)(ws + off);             off += NBUCKET * 4;                    // 128 KB
    int* keyS = (int*)(ws + off);             off += 2097152;                        // 2 MB
    int* origId = (int*)(ws + off);           off += 2097152;                        // 2 MB
    unsigned short* featsB = (unsigned short*)(ws + off);                            // 32 MB + 64 B

    hipMemsetAsync(table, 0xFF, (size_t)GRID * GRID * GRID * 4, stream);
    hipMemsetAsync(hist, 0, NBUCKET * 4, stream);
    hipMemsetAsync(featsB, 0, CIN * sizeof(unsigned short), stream);  // zero row 0

    int blocksN = (N + 255) / 256;
    hist_kernel<<<blocksN, 256, 0, stream>>>(pos, wt, table, hist, wtT, N);
    scan_kernel<<<1, 1024, 0, stream>>>(hist);
    scatter_kernel<<<blocksN, 256, 0, stream>>>(pos, hist, table, keyS, origId,
                                                feats, featsB, N);

    int numTiles = (N + 15) / 16;
    int nwg = (numTiles + 7) / 8;     // 8 waves (512 threads) per block
    conv_kernel<<<nwg, 512, 0, stream>>>(featsB, keyS, wtT, table, origId, out, N);
}

// Round 8
// 255.915 us; speedup vs baseline: 1.2830x; 1.2706x over previous
//
#include <hip/hip_runtime.h>

// Submanifold sparse conv 3x3x3, G=128, Cin=Cout=32.
// R14: proven-footprint 3-node structure + occupancy-targeted conv.
// Evidence: R13 (48.1MB workspace) killed the container twice; largest
// proven footprint is 44.26MB -> revert to R0's 40.07MB layout (8MB int32
// table + memset + 64KB wtT + 32MB featsB). Conv was stuck at ~121us with
// 16 waves/CU (LDS 55.3KB -> 2 blocks/CU). This round: 26 k-slices in LDS
// (53248B -> 3 blocks/CU = 24 waves, +50% TLP); center tap k=13 computed
// via compiler loads BEFORE the asm region (count-safe: unaware compiler
// only over-waits); saddr-form asm gathers with precomputed byte voffsets
// (no per-step addr math); depth-6 rolling window, counted WAITV(5);
// conflict-free LDS weight layout; zero-row for invalid neighbors.
// Canary: a VGPR spill inside the loop would corrupt vmcnt -> absmax fail.

#define GRID 128
#define CIN 32
#define COUT 32
#define NOFF 27

typedef __attribute__((ext_vector_type(8))) short bf16x8;
typedef __attribute__((ext_vector_type(4))) float f32x4;

__device__ inline unsigned short f2bf(float x) {
    union { float f; unsigned u; } v; v.f = x;
    unsigned r = v.u + 0x7fff + ((v.u >> 16) & 1);   // RTNE
    return (unsigned short)(r >> 16);
}

// K1: fused prep (one dispatch):
//  - feats fp32 -> bf16 rows shifted +1 (row 0 = zeros, threads 0..7 clear it)
//  - table atomicMax (numpy max-index-wins), table pre-memset to -1
//  - weight transpose [27][ci][co] -> [k][half(co>=16)][quad(ci>>3)][m][e]
__global__ void prep_kernel(const float* __restrict__ feats,
                            const int* __restrict__ pos,
                            const float* __restrict__ wt,
                            int* __restrict__ table,
                            unsigned short* __restrict__ wtT,
                            unsigned* __restrict__ featsB,
                            int N, int elems4) {
    int i = blockIdx.x * 256 + threadIdx.x;
    if (i < elems4) {                      // 4 fp32 -> 4 bf16 per thread
        float4 v = ((const float4*)feats)[i];
        uint2 o;
        o.x = (unsigned)f2bf(v.x) | ((unsigned)f2bf(v.y) << 16);
        o.y = (unsigned)f2bf(v.z) | ((unsigned)f2bf(v.w) << 16);
        ((uint2*)featsB)[i + 8] = o;       // +8 uint2 = +32 bf16 = one row
    }
    if (i < 8) ((uint2*)featsB)[i] = (uint2){0u, 0u};   // zero row 0
    if (i < N) {
        int x = pos[3 * i], y = pos[3 * i + 1], z = pos[3 * i + 2];
        atomicMax(&table[(x * GRID + y) * GRID + z], i);
    }
    if (i < NOFF * CIN * COUT) {
        int k = i >> 10, r = i & 1023, ci = r >> 5, co = r & 31;
        int d = k * 1024 + (co >= 16 ? 512 : 0) + (ci >> 3) * 128 + (co & 15) * 8 + (ci & 7);
        wtT[d] = f2bf(wt[i]);
    }
}

// K2: implicit-GEMM conv, one 16-pt tile per wave, 8 waves/block, 3 blk/CU.
#define SBAR() __builtin_amdgcn_sched_barrier(0)
#define WAITV(n) asm volatile("s_waitcnt vmcnt(" #n ")" ::: "memory")
// saddr form: 32-bit byte voffset (VGPR) + 64-bit base (SGPR pair)
#define GLOAD(dst, ss) \
    asm volatile("global_load_dwordx4 %0, %1, %2" \
                 : "=v"(dst) : "v"(voff[ss]), "s"(featsB));

#define STEPL(areg, kk) { \
    bf16x8 b0_ = *(const bf16x8*)(wb + (kk) * 1024); \
    bf16x8 b1_ = *(const bf16x8*)(wb + (kk) * 1024 + 512); \
    acc0 = __builtin_amdgcn_mfma_f32_16x16x32_bf16(areg, b0_, acc0, 0, 0, 0); \
    acc1 = __builtin_amdgcn_mfma_f32_16x16x32_bf16(areg, b1_, acc1, 0, 0, 0); }

__global__ __launch_bounds__(512, 6)
void conv_kernel(const unsigned short* __restrict__ featsB,
                 const int* __restrict__ pos,
                 const unsigned short* __restrict__ wtT,
                 const int* __restrict__ table,
                 float* __restrict__ out, int N) {
    __shared__ __align__(16) unsigned short ldsw[26 * 1024]; // 53248 B -> 3 blk/CU

    int tid = threadIdx.x;
    int wave = tid >> 6, lane = tid & 63;
    int m = lane & 15, quad = lane >> 4;
    int tile = (int)blockIdx.x * 8 + wave;
    int base = tile * 16;
    int g = base + m;
    bool gv = g < N;

    int x = 0, y = 0, z = 0;
    if (gv) { x = pos[3 * g]; y = pos[3 * g + 1]; z = pos[3 * g + 2]; }
    int key = (x * GRID + y) * GRID + z;
    bool v0[3] = {gv && x > 0, gv, gv && x < GRID - 1};
    bool v1[3] = {gv && y > 0, gv, gv && y < GRID - 1};
    bool v2[3] = {gv && z > 0, gv, gv && z < GRID - 1};

    // Phase A: 26 ring-tap table lookups -> byte voffsets (skip k=13).
    // voff = (id+1)*64 + quad*16 when valid else row 0 (quad*16).
    int qb = quad * 16;
    int voff[26];
#pragma unroll
    for (int s = 0; s < 26; ++s) {
        const int k = s + (s >= 13);
        const int dx = k / 9, dy = (k / 3) % 3, dz = k % 3;
        bool ok = v0[dx] && v1[dy] && v2[dz];
        int hk = key + (dx - 1) * GRID * GRID + (dy - 1) * GRID + (dz - 1);
        hk = ok ? hk : 0;
        int id = table[hk];
        voff[s] = ((ok && id >= 0) ? (id + 1) * 64 : 0) + qb;
    }

    f32x4 acc0 = {0.f, 0.f, 0.f, 0.f};
    f32x4 acc1 = {0.f, 0.f, 0.f, 0.f};

    // Center tap (k=13): compiler loads + 2 MFMA, fully before the asm
    // region (compiler waitcnts can only over-wait -> count-safe).
    {
        int idc = table[key];                       // own voxel's winner
        int vc = ((gv && idc >= 0) ? (idc + 1) * 64 : 0) + qb;
        bf16x8 ac = *(const bf16x8*)((const char*)featsB + vc);
        const unsigned short* wc = wtT + 13 * 1024 + quad * 128 + m * 8;
        bf16x8 wc0 = *(const bf16x8*)(wc);
        bf16x8 wc1 = *(const bf16x8*)(wc + 512);
        acc0 = __builtin_amdgcn_mfma_f32_16x16x32_bf16(ac, wc0, acc0, 0, 0, 0);
        acc1 = __builtin_amdgcn_mfma_f32_16x16x32_bf16(ac, wc1, acc1, 0, 0, 0);
    }
    SBAR();   // pin the center compute above the asm pipeline

    bf16x8 c0, c1, c2, c3, c4, c5;
    // Prologue: gathers 0..5 in flight; latency hides under LDS staging
    // (the staging barrier drains them - they're ready at loop entry).
    GLOAD(c0, 0) GLOAD(c1, 1) GLOAD(c2, 2)
    GLOAD(c3, 3) GLOAD(c4, 4) GLOAD(c5, 5)

    // Stage 26 W^T slices (k != 13) into LDS; remap source index.
    {
        const uint4* src = (const uint4*)wtT;       // [27][128] uint4
        uint4* dst = (uint4*)ldsw;                  // [26][128] uint4
        for (int e = tid; e < 26 * 128; e += 512) {
            int ks = e >> 7; ks += (ks >= 13);
            dst[e] = src[ks * 128 + (e & 127)];
        }
    }
    __syncthreads();

    // conflict-free: 16-lane phase (quad fixed) reads 16 contiguous 16B slots
    const unsigned short* wb = ldsw + quad * 128 + m * 8;

    // Steady state: consume buf s%6, reload gather s+6; counted vmcnt.
    WAITV(5); SBAR(); STEPL(c0, 0)  GLOAD(c0, 6)
    WAITV(5); SBAR(); STEPL(c1, 1)  GLOAD(c1, 7)
    WAITV(5); SBAR(); STEPL(c2, 2)  GLOAD(c2, 8)
    WAITV(5); SBAR(); STEPL(c3, 3)  GLOAD(c3, 9)
    WAITV(5); SBAR(); STEPL(c4, 4)  GLOAD(c4, 10)
    WAITV(5); SBAR(); STEPL(c5, 5)  GLOAD(c5, 11)
    WAITV(5); SBAR(); STEPL(c0, 6)  GLOAD(c0, 12)
    WAITV(5); SBAR(); STEPL(c1, 7)  GLOAD(c1, 13)
    WAITV(5); SBAR(); STEPL(c2, 8)  GLOAD(c2, 14)
    WAITV(5); SBAR(); STEPL(c3, 9)  GLOAD(c3, 15)
    WAITV(5); SBAR(); STEPL(c4, 10) GLOAD(c4, 16)
    WAITV(5); SBAR(); STEPL(c5, 11) GLOAD(c5, 17)
    WAITV(5); SBAR(); STEPL(c0, 12) GLOAD(c0, 18)
    WAITV(5); SBAR(); STEPL(c1, 13) GLOAD(c1, 19)
    WAITV(5); SBAR(); STEPL(c2, 14) GLOAD(c2, 20)
    WAITV(5); SBAR(); STEPL(c3, 15) GLOAD(c3, 21)
    WAITV(5); SBAR(); STEPL(c4, 16) GLOAD(c4, 22)
    WAITV(5); SBAR(); STEPL(c5, 17) GLOAD(c5, 23)
    WAITV(5); SBAR(); STEPL(c0, 18) GLOAD(c0, 24)
    WAITV(5); SBAR(); STEPL(c1, 19) GLOAD(c1, 25)
    WAITV(5); SBAR(); STEPL(c2, 20)
    WAITV(4); SBAR(); STEPL(c3, 21)
    WAITV(3); SBAR(); STEPL(c4, 22)
    WAITV(2); SBAR(); STEPL(c5, 23)
    WAITV(1); SBAR(); STEPL(c0, 24)
    WAITV(0); SBAR(); STEPL(c1, 25)

    // D layout: col = lane&15 = co, row = quad*4 + i = point within tile.
    // Original order -> coalesced 64B output row segments.
#pragma unroll
    for (int i = 0; i < 4; ++i) {
        int p = base + quad * 4 + i;
        if (p < N) {
            out[(size_t)p * COUT + m]      = acc0[i];
            out[(size_t)p * COUT + m + 16] = acc1[i];
        }
    }
}

extern "C" void kernel_launch(void* const* d_in, const int* in_sizes, int n_in,
                              void* d_out, int out_size, void* d_ws, size_t ws_size,
                              hipStream_t stream) {
    const float* feats = (const float*)d_in[0];   // [N, 32]
    const int*   pos   = (const int*)d_in[1];     // [N, 3]
    const float* wt    = (const float*)d_in[2];   // [27, 32, 32]
    float* out = (float*)d_out;                   // [N, 32]
    int N = in_sizes[0] / CIN;

    char* ws = (char*)d_ws;
    size_t off = 0;
    int* table = (int*)(ws + off);            off += (size_t)GRID * GRID * GRID * 4; // 8 MB
    unsigned short* wtT = (unsigned short*)(ws + off); off += 65536;                 // 64 KB
    unsigned* featsB = (unsigned*)(ws + off);                             // 32 MB + 64 B

    hipMemsetAsync(table, 0xFF, (size_t)GRID * GRID * GRID * 4, stream);

    int elems4 = N * CIN / 4;   // 4M threads covers feats; N and wt smaller
    prep_kernel<<<(elems4 + 255) / 256, 256, 0, stream>>>(
        feats, pos, wt, table, wtT, featsB, N, elems4);

    int numTiles = (N + 15) / 16;
    int nwg = (numTiles + 7) / 8;     // 8 waves (512 threads) per block
    conv_kernel<<<nwg, 512, 0, stream>>>((const unsigned short*)featsB, pos, wtT,
                                         table, out, N);
}